// Round 6
// baseline (184.259 us; speedup 1.0000x reference)
//
#include <hip/hip_runtime.h>
#include <hip/hip_bf16.h>
#include <math.h>

#define B 32
#define T 1024
#define AC 20
#define SE 16
#define H 64
#define NH 4
#define HD 16
#define NROW (B*T)      // 32768
#define BH (B*NH)       // 128
#define KS 2            // key-split factor
#define KSLICE (T/KS)   // 512
#define NCH (KSLICE/32) // 16 chunks of 32 keys

typedef unsigned short u16;
typedef short short8 __attribute__((ext_vector_type(8)));
typedef float floatx4 __attribute__((ext_vector_type(4)));

// ---- workspace layout (float offsets) ----
#define F_QB   (BH*T*16/2)                   // bf16 tensor of BH*T*16 elems in float units
#define OFF_QB   0
#define OFF_KB   (OFF_QB + F_QB)
#define OFF_VT   (OFF_KB + F_QB)             // bf16 Vt [bh][hd][t'] slot-interleaved
#define OFF_PART (OFF_VT + F_QB)             // f32 [KS][bh][t][16]
#define OFF_PARTL (OFF_PART + KS*BH*T*16)    // f32 [KS][bh][t]
#define OFF_ET   (OFF_PARTL + KS*BH*T)
#define OFF_AT   (OFF_ET + AC*NROW)
#define OFF_WF   (OFF_AT + AC*NROW)
#define OFF_PST  (OFF_WF + 5120)             // 20*64*4 floats
#define OFF_END  (OFF_PST + 20*64*4)

// fused-weight sub-offsets inside wf
#define WF_WQ 0
#define WF_BQ 1024
#define WF_WK 1088
#define WF_BK 2368
#define WF_WV 2432
#define WF_BV 3712
#define WF_WO 3776
#define WF_BO 5056
#define WF_TOTAL 5076

__device__ __forceinline__ u16 bf16b(float a) {
    __hip_bfloat16 t = __float2bfloat16(a);
    u16 u; __builtin_memcpy(&u, &t, 2); return u;
}
__device__ __forceinline__ unsigned packbf(float a, float b) {
    return (unsigned)bf16b(a) | ((unsigned)bf16b(b) << 16);
}

// ---------------- K0: fuse weights ----------------
__global__ __launch_bounds__(256) void k_fuse(
    const float* __restrict__ Wq, const float* __restrict__ bq,
    const float* __restrict__ Wkv, const float* __restrict__ bkv,
    const float* __restrict__ in_w, const float* __restrict__ in_b,
    const float* __restrict__ out_w, const float* __restrict__ out_b,
    const float* __restrict__ proj_w, const float* __restrict__ proj_b,
    float* __restrict__ wf) {
    int idx = blockIdx.x * 256 + threadIdx.x;
    if (idx >= WF_TOTAL) return;
    if (idx < WF_BQ) {                       // WqF[i][j] (scale 0.25 folded)
        int i = idx >> 4, j = idx & 15;
        float s = 0.f;
        for (int m = 0; m < H; ++m) s += in_w[i*H + m] * Wq[m*SE + j];
        wf[idx] = 0.25f * s;
    } else if (idx < WF_WK) {                // bqF
        int i = idx - WF_BQ;
        float s = in_b[i];
        for (int m = 0; m < H; ++m) s += in_w[i*H + m] * bq[m];
        wf[idx] = 0.25f * s;
    } else if (idx < WF_BK) {                // WkF[i][j]
        int r = idx - WF_WK; int i = r / AC, j = r % AC;
        float s = 0.f;
        for (int m = 0; m < H; ++m) s += in_w[(H+i)*H + m] * Wkv[m*AC + j];
        wf[idx] = s;
    } else if (idx < WF_WV) {                // bkF
        int i = idx - WF_BK;
        float s = in_b[H + i];
        for (int m = 0; m < H; ++m) s += in_w[(H+i)*H + m] * bkv[m];
        wf[idx] = s;
    } else if (idx < WF_BV) {                // WvF[i][j]
        int r = idx - WF_WV; int i = r / AC, j = r % AC;
        float s = 0.f;
        for (int m = 0; m < H; ++m) s += in_w[(2*H+i)*H + m] * Wkv[(H+m)*AC + j];
        wf[idx] = s;
    } else if (idx < WF_WO) {                // bvF
        int i = idx - WF_BV;
        float s = in_b[2*H + i];
        for (int m = 0; m < H; ++m) s += in_w[(2*H+i)*H + m] * bkv[H + m];
        wf[idx] = s;
    } else if (idx < WF_BO) {                // WoF[c][d]
        int r = idx - WF_WO; int c = r >> 6, d = r & 63;
        float s = 0.f;
        for (int m = 0; m < H; ++m) s += proj_w[c*H + m] * out_w[m*H + d];
        wf[idx] = s;
    } else {                                 // boF
        int c = idx - WF_BO;
        float s = proj_b[c];
        for (int m = 0; m < H; ++m) s += proj_w[c*H + m] * out_b[m];
        wf[idx] = s;
    }
}

// ---------------- K1: fused QKV projection (wave-specialized, 12 sections/row) ----------------
// block = 192 threads = 16 rows x 12 sections; wave0=Q(4 heads), wave1=K, wave2=V
__global__ __launch_bounds__(192) void k_qkv(
    const float* __restrict__ sem, const float* __restrict__ acst,
    const float* __restrict__ wf,
    u16* __restrict__ Qb, u16* __restrict__ Kb, u16* __restrict__ Vtb) {
    const int tid = threadIdx.x;
    const int sec = tid >> 4, r = tid & 15;
    const int row = blockIdx.x * 16 + r;
    const int b = row >> 10, t = row & 1023;
    const int type = sec >> 2, h = sec & 3;
    float o[16];
    if (type == 0) {
        float s[SE];
        const float4* sp = (const float4*)(sem + (size_t)row * SE);
        #pragma unroll
        for (int i = 0; i < 4; ++i) {
            float4 v = sp[i];
            s[4*i] = v.x; s[4*i+1] = v.y; s[4*i+2] = v.z; s[4*i+3] = v.w;
        }
        const float* wq = wf + WF_WQ + h*16*SE;
        const float* bq = wf + WF_BQ + h*16;
        #pragma unroll
        for (int ii = 0; ii < 16; ++ii) {
            float acc = bq[ii];
            #pragma unroll
            for (int j = 0; j < 4; ++j) {
                float4 w4 = *(const float4*)(wq + ii*SE + 4*j);
                acc += s[4*j]*w4.x + s[4*j+1]*w4.y + s[4*j+2]*w4.z + s[4*j+3]*w4.w;
            }
            o[ii] = acc;
        }
        unsigned* dst = (unsigned*)(Qb + (((size_t)(b*NH + h))*T + t)*16);
        #pragma unroll
        for (int i = 0; i < 8; ++i) dst[i] = packbf(o[2*i], o[2*i+1]);
    } else {
        float a[AC];
        const float4* ap = (const float4*)(acst + (size_t)row * AC);
        #pragma unroll
        for (int i = 0; i < 5; ++i) {
            float4 v = ap[i];
            a[4*i] = v.x; a[4*i+1] = v.y; a[4*i+2] = v.z; a[4*i+3] = v.w;
        }
        const float* wb = wf + (type == 1 ? WF_WK : WF_WV) + h*16*AC;
        const float* bb = wf + (type == 1 ? WF_BK : WF_BV) + h*16;
        #pragma unroll
        for (int ii = 0; ii < 16; ++ii) {
            float acc = bb[ii];
            #pragma unroll
            for (int j = 0; j < 5; ++j) {
                float4 w4 = *(const float4*)(wb + ii*AC + 4*j);
                acc += a[4*j]*w4.x + a[4*j+1]*w4.y + a[4*j+2]*w4.z + a[4*j+3]*w4.w;
            }
            o[ii] = acc;
        }
        if (type == 1) {
            unsigned* dst = (unsigned*)(Kb + (((size_t)(b*NH + h))*T + t)*16);
            #pragma unroll
            for (int i = 0; i < 8; ++i) dst[i] = packbf(o[2*i], o[2*i+1]);
        } else {
            int w32 = t & 31;
            int slot = (w32 < 16) ? (w32*2) : ((w32-16)*2 + 1);
            int tp = (t & ~31) | slot;
            #pragma unroll
            for (int d = 0; d < HD; ++d)
                Vtb[((size_t)(b*NH + h)*16 + d)*T + tp] = bf16b(o[d]);
        }
    }
}

// ---------------- K2: MFMA flash attention ----------------
// block = 8 waves (512 thr); wave = 16 q-rows x 512-key slice
// grid = 2048: idx bits = [0:3)=bh-low, [3:7)=qs (ks,qb), [7:11)=bh-high
__global__ __launch_bounds__(512) void k_attn(
    const u16* __restrict__ Qb, const u16* __restrict__ Kb, const u16* __restrict__ Vtb,
    float* __restrict__ part, float* __restrict__ partL) {
    __shared__ __align__(16) uint4 Ks2[KSLICE*2];   // 16 KB, fragment order (identity copy)
    __shared__ __align__(16) uint4 Vs2[NCH*64];     // 16 KB, [chunk][lane] permuted
    __shared__ __align__(16) u16 Ps[8*16*40];       // 10 KB (per-wave 16x40)
    const int tid = threadIdx.x;
    const int idx = blockIdx.x;
    const int bh = (idx & 7) + 8 * (idx >> 7);
    const int qs = (idx >> 3) & 15;
    const int ks = qs & 1;
    const int qb = qs >> 1;
    const int kbase = ks * KSLICE;
    const int wv = tid >> 6, lane = tid & 63;
    const int col = lane & 15, quad = lane >> 4;
    const int q0 = qb*128 + wv*16;
    // Q fragment from global (overlaps staging; independent of LDS)
    short8 qf = {0,0,0,0,0,0,0,0};
    if (quad < 2)
        qf = *(const short8*)(Qb + ((size_t)bh*T + q0 + col)*16 + quad*8);
    // stage K (identity copy -> fragment order) and V (permuted [chunk][lane])
    {
        const uint4* ksrc = (const uint4*)(Kb + ((size_t)bh*T + kbase)*16);
        #pragma unroll
        for (int s = tid; s < KSLICE*2; s += 512) Ks2[s] = ksrc[s];
        #pragma unroll
        for (int s = tid; s < NCH*64; s += 512) {
            int ch = s >> 6, ln = s & 63, d = ln & 15, qd = ln >> 4;
            Vs2[s] = *(const uint4*)(Vtb + ((size_t)(bh*16 + d))*T + kbase + ch*32 + qd*8);
        }
    }
    __syncthreads();
    const floatx4 z4 = {0.f,0.f,0.f,0.f};
    floatx4 acc = z4;
    float ls[4] = {0.f,0.f,0.f,0.f};
    u16* Pw = &Ps[wv*640];
    for (int ch = 0; ch < NCH; ++ch) {
        short8 kf0 = {0,0,0,0,0,0,0,0}, kf1 = {0,0,0,0,0,0,0,0};
        if (quad < 2) {
            kf0 = *(const short8*)&Ks2[ch*64 + col*2 + quad];
            kf1 = *(const short8*)&Ks2[ch*64 + 32 + col*2 + quad];
        }
        floatx4 s0 = __builtin_amdgcn_mfma_f32_16x16x32_bf16(qf, kf0, z4, 0, 0, 0);
        floatx4 s1 = __builtin_amdgcn_mfma_f32_16x16x32_bf16(qf, kf1, z4, 0, 0, 0);
        float p0[4], p1[4];
        #pragma unroll
        for (int r = 0; r < 4; ++r) {
            p0[r] = __expf(s0[r]); p1[r] = __expf(s1[r]);
            ls[r] += p0[r] + p1[r];
        }
        #pragma unroll
        for (int r = 0; r < 4; ++r)
            *(unsigned*)&Pw[(quad*4 + r)*40 + col*2] = packbf(p0[r], p1[r]);
        short8 pf = *(const short8*)&Pw[col*40 + quad*8];
        short8 vf = *(const short8*)&Vs2[ch*64 + lane];
        acc = __builtin_amdgcn_mfma_f32_16x16x32_bf16(pf, vf, acc, 0, 0, 0);
    }
    float* dst = part + (((size_t)ks*BH + bh)*T + q0)*16;
    #pragma unroll
    for (int r = 0; r < 4; ++r) dst[(quad*4 + r)*16 + col] = acc[r];
    #pragma unroll
    for (int m = 1; m < 16; m <<= 1) {
        #pragma unroll
        for (int r = 0; r < 4; ++r) ls[r] += __shfl_xor(ls[r], m);
    }
    if (col == 0) {
        float* ld = partL + ((size_t)ks*BH + bh)*T + q0 + quad*4;
        #pragma unroll
        for (int r = 0; r < 4; ++r) ld[r] = ls[r];
    }
}

// ---------------- K3: combine partials + output proj + residual ----------------
// block = 320 threads, 32 rows; phase2: thread = (row, 2 channels); grid 1024
#define CSTR 65
__global__ __launch_bounds__(320) void k_proj(
    const float* __restrict__ part, const float* __restrict__ partL,
    const float* __restrict__ acst, const float* __restrict__ wf,
    const float* __restrict__ rlogit,
    float* __restrict__ enhT, float* __restrict__ aT) {
    __shared__ float ctxs[32*CSTR];                 // 8.3 KB
    __shared__ __align__(16) float wsm[AC*H + AC];  // 5.2 KB
    const int tid = threadIdx.x;
    if (tid >= 128) {  // phase-1-idle threads preload weights
        for (int i = tid - 128; i < AC*H + AC; i += 192) wsm[i] = wf[WF_WO + i];
    } else {
        const int r = tid & 31, h = tid >> 5;
        const int row = blockIdx.x*32 + r;
        const int b = row >> 10, t = row & 1023;
        const int bh = b*NH + h;
        float l = partL[(size_t)bh*T + t] + partL[(size_t)(BH + bh)*T + t];
        float inv = 1.f / l;
        const float4* pa = (const float4*)(part + ((size_t)bh*T + t)*16);
        const float4* pb = (const float4*)(part + ((size_t)(BH + bh)*T + t)*16);
        float* cd = &ctxs[r*CSTR + h*16];
        #pragma unroll
        for (int i = 0; i < 4; ++i) {
            float4 x = pa[i], y = pb[i];
            cd[4*i+0] = (x.x + y.x)*inv;
            cd[4*i+1] = (x.y + y.y)*inv;
            cd[4*i+2] = (x.z + y.z)*inv;
            cd[4*i+3] = (x.w + y.w)*inv;
        }
    }
    __syncthreads();
    const int r = tid & 31, cp = tid >> 5;   // cp in [0,10)
    const int row = blockIdx.x*32 + r;
    const int ch0 = cp*2, ch1 = cp*2 + 1;
    float s0 = wsm[AC*H + ch0], s1 = wsm[AC*H + ch1];
    const float4* w0 = (const float4*)(wsm + ch0*H);
    const float4* w1 = (const float4*)(wsm + ch1*H);
    const float* cr = &ctxs[r*CSTR];
    #pragma unroll
    for (int k = 0; k < 16; ++k) {
        float4 c4 = *(const float4*)(cr + 4*k);
        float4 a4 = w0[k], b4 = w1[k];
        s0 += c4.x*a4.x + c4.y*a4.y + c4.z*a4.z + c4.w*a4.w;
        s1 += c4.x*b4.x + c4.y*b4.y + c4.z*b4.z + c4.w*b4.w;
    }
    float sg = 1.f / (1.f + __expf(-rlogit[0]));
    float a0 = acst[(size_t)row*AC + ch0];
    float a1 = acst[(size_t)row*AC + ch1];
    float e0 = a0 + sg * s0, e1 = a1 + sg * s1;
    enhT[(size_t)ch0 * NROW + row] = e0;
    enhT[(size_t)ch1 * NROW + row] = e1;
    aT[(size_t)ch0 * NROW + row] = a0;
    aT[(size_t)ch1 * NROW + row] = a1;
}

// ---------------- K4: per-channel partial stats (64 slices/channel) ----------------
__global__ __launch_bounds__(256) void k_stats1(
    const float* __restrict__ aT, const float* __restrict__ enhT,
    float* __restrict__ pst) {
    int c = blockIdx.x >> 6, sl = blockIdx.x & 63;
    int base = sl * 512;
    const float* ac = aT  + (size_t)c*NROW + base;
    const float* ec = enhT + (size_t)c*NROW + base;
    int tid = threadIdx.x;
    float a0 = ac[tid], a1 = ac[tid + 256];
    float e0 = ec[tid], e1 = ec[tid + 256];
    float sa = a0 + a1, qa = a0*a0 + a1*a1;
    float se = e0 + e1, qe = e0*e0 + e1*e1;
    #pragma unroll
    for (int off = 32; off > 0; off >>= 1) {
        sa += __shfl_down(sa, off);
        qa += __shfl_down(qa, off);
        se += __shfl_down(se, off);
        qe += __shfl_down(qe, off);
    }
    __shared__ float rs[4][4];
    int w = tid >> 6;
    if ((tid & 63) == 0) { rs[w][0] = sa; rs[w][1] = qa; rs[w][2] = se; rs[w][3] = qe; }
    __syncthreads();
    if (tid == 0) {
        float A = 0.f, QA = 0.f, E = 0.f, QE = 0.f;
        for (int i = 0; i < 4; ++i) { A += rs[i][0]; QA += rs[i][1]; E += rs[i][2]; QE += rs[i][3]; }
        float* d = pst + (size_t)(c*64 + sl)*4;
        d[0] = A; d[1] = QA; d[2] = E; d[3] = QE;
    }
}

// ---------------- K5: combine stats + std-correction + LayerNorm ----------------
__global__ __launch_bounds__(128) void k_final(
    const float* __restrict__ enhT, const float* __restrict__ pst,
    const float* __restrict__ gamma, const float* __restrict__ beta,
    float* __restrict__ out) {
    __shared__ float acc_s[80];
    for (int i = threadIdx.x; i < 80; i += 128) {
        int c = i >> 2, j = i & 3;
        float s = 0.f;
        for (int sl = 0; sl < 64; ++sl) s += pst[(size_t)(c*64 + sl)*4 + j];
        acc_s[i] = s;
    }
    __syncthreads();
    int row = blockIdx.x * 128 + threadIdx.x;
    const float Nf = (float)NROW;
    float ef[AC];
    #pragma unroll
    for (int c = 0; c < AC; ++c) {
        float sa = acc_s[c*4+0], qa = acc_s[c*4+1];
        float se = acc_s[c*4+2], qe = acc_s[c*4+3];
        float mu  = sa / Nf;
        float va  = (qa - sa*sa/Nf) / (Nf - 1.f);
        float sda = sqrtf(fmaxf(va, 0.f));
        float osd = sda + 1e-8f;
        float ve  = (qe - se*se/Nf) / (Nf - 1.f);
        float sde = sqrtf(fmaxf(ve, 0.f));
        float ratio = (sde / osd) / (sda / osd + 1e-8f);
        float corr  = (ratio < 0.4f) ? (0.4f / ratio) : 1.f;
        float e = enhT[(size_t)c * NROW + row];
        ef[c] = (e - mu) * corr + mu;
    }
    float m = 0.f;
    #pragma unroll
    for (int c = 0; c < AC; ++c) m += ef[c];
    m *= (1.f / AC);
    float v = 0.f;
    #pragma unroll
    for (int c = 0; c < AC; ++c) { float d = ef[c] - m; v += d*d; }
    v *= (1.f / AC);
    float inv = rsqrtf(v + 1e-5f);
    float o[AC];
    #pragma unroll
    for (int c = 0; c < AC; ++c) o[c] = (ef[c] - m) * inv * gamma[c] + beta[c];
    float4* op = (float4*)(out + (size_t)row * AC);
    #pragma unroll
    for (int i = 0; i < 5; ++i)
        op[i] = make_float4(o[4*i], o[4*i+1], o[4*i+2], o[4*i+3]);
}

extern "C" void kernel_launch(void* const* d_in, const int* in_sizes, int n_in,
                              void* d_out, int out_size, void* d_ws, size_t ws_size,
                              hipStream_t stream) {
    (void)in_sizes; (void)n_in; (void)out_size; (void)ws_size;
    const float* acoustic = (const float*)d_in[0];
    const float* semantic = (const float*)d_in[1];
    const float* Wq     = (const float*)d_in[2];
    const float* bq     = (const float*)d_in[3];
    const float* Wkv    = (const float*)d_in[4];
    const float* bkv    = (const float*)d_in[5];
    const float* in_w   = (const float*)d_in[6];
    const float* in_b   = (const float*)d_in[7];
    const float* out_w  = (const float*)d_in[8];
    const float* out_b  = (const float*)d_in[9];
    const float* proj_w = (const float*)d_in[10];
    const float* proj_b = (const float*)d_in[11];
    const float* rlogit = (const float*)d_in[12];
    const float* gamma  = (const float*)d_in[13];
    const float* beta   = (const float*)d_in[14];
    float* ws = (float*)d_ws;
    u16* Qb  = (u16*)(ws + OFF_QB);
    u16* Kb  = (u16*)(ws + OFF_KB);
    u16* Vtb = (u16*)(ws + OFF_VT);
    float* part  = ws + OFF_PART;
    float* partL = ws + OFF_PARTL;
    float* enhT  = ws + OFF_ET;
    float* aT    = ws + OFF_AT;
    float* wf    = ws + OFF_WF;
    float* pst   = ws + OFF_PST;
    float* out = (float*)d_out;

    k_fuse<<<(WF_TOTAL + 255)/256, 256, 0, stream>>>(Wq, bq, Wkv, bkv, in_w, in_b,
                                                     out_w, out_b, proj_w, proj_b, wf);
    k_qkv<<<NROW/16, 192, 0, stream>>>(semantic, acoustic, wf, Qb, Kb, Vtb);
    k_attn<<<BH*8*KS, 512, 0, stream>>>(Qb, Kb, Vtb, part, partL);
    k_proj<<<NROW/32, 320, 0, stream>>>(part, partL, acoustic, wf, rlogit, enhT, aT);
    k_stats1<<<AC*64, 256, 0, stream>>>(aT, enhT, pst);
    k_final<<<NROW/128, 128, 0, stream>>>(enhT, pst, gamma, beta, out);
}

// Round 7
// 180.669 us; speedup vs baseline: 1.0199x; 1.0199x over previous
//
#include <hip/hip_runtime.h>
#include <hip/hip_bf16.h>
#include <math.h>

#define B 32
#define T 1024
#define AC 20
#define SE 16
#define H 64
#define NH 4
#define HD 16
#define NROW (B*T)      // 32768
#define BH (B*NH)       // 128
#define KS 2            // key-split factor
#define KSLICE (T/KS)   // 512
#define NCH (KSLICE/32) // 16 chunks of 32 keys

typedef unsigned short u16;
typedef short short8 __attribute__((ext_vector_type(8)));
typedef float floatx4 __attribute__((ext_vector_type(4)));

// ---- workspace layout (float offsets) ----
#define F_QB   (BH*T*16/2)                   // bf16 tensor of BH*T*16 elems in float units
#define OFF_QB   0
#define OFF_KB   (OFF_QB + F_QB)
#define OFF_VT   (OFF_KB + F_QB)             // bf16 Vt [bh][hd][t'] slot-interleaved
#define OFF_PART (OFF_VT + F_QB)             // f32 [KS][bh][t][16]
#define OFF_PARTL (OFF_PART + KS*BH*T*16)    // f32 [KS][bh][t]
#define OFF_ET   (OFF_PARTL + KS*BH*T)
#define OFF_AT   (OFF_ET + AC*NROW)
#define OFF_WF   (OFF_AT + AC*NROW)
#define OFF_PST  (OFF_WF + 5120)             // 20*64*4 floats
#define OFF_END  (OFF_PST + 20*64*4)

// fused-weight sub-offsets inside wf
#define WF_WQ 0
#define WF_BQ 1024
#define WF_WK 1088
#define WF_BK 2368
#define WF_WV 2432
#define WF_BV 3712
#define WF_WO 3776
#define WF_BO 5056
#define WF_TOTAL 5076

#define QSCALE 0.3606738f   // 0.25 * log2(e) folded into Wq

__device__ __forceinline__ u16 bf16b(float a) {
    __hip_bfloat16 t = __float2bfloat16(a);
    u16 u; __builtin_memcpy(&u, &t, 2); return u;
}
__device__ __forceinline__ unsigned packbf(float a, float b) {
    return (unsigned)bf16b(a) | ((unsigned)bf16b(b) << 16);
}

// ---------------- K0: fuse weights ----------------
__global__ __launch_bounds__(256) void k_fuse(
    const float* __restrict__ Wq, const float* __restrict__ bq,
    const float* __restrict__ Wkv, const float* __restrict__ bkv,
    const float* __restrict__ in_w, const float* __restrict__ in_b,
    const float* __restrict__ out_w, const float* __restrict__ out_b,
    const float* __restrict__ proj_w, const float* __restrict__ proj_b,
    float* __restrict__ wf) {
    int idx = blockIdx.x * 256 + threadIdx.x;
    if (idx >= WF_TOTAL) return;
    if (idx < WF_BQ) {                       // WqF[i][j] (0.25*log2e folded)
        int i = idx >> 4, j = idx & 15;
        float s = 0.f;
        for (int m = 0; m < H; ++m) s += in_w[i*H + m] * Wq[m*SE + j];
        wf[idx] = QSCALE * s;
    } else if (idx < WF_WK) {                // bqF
        int i = idx - WF_BQ;
        float s = in_b[i];
        for (int m = 0; m < H; ++m) s += in_w[i*H + m] * bq[m];
        wf[idx] = QSCALE * s;
    } else if (idx < WF_BK) {                // WkF[i][j]
        int r = idx - WF_WK; int i = r / AC, j = r % AC;
        float s = 0.f;
        for (int m = 0; m < H; ++m) s += in_w[(H+i)*H + m] * Wkv[m*AC + j];
        wf[idx] = s;
    } else if (idx < WF_WV) {                // bkF
        int i = idx - WF_BK;
        float s = in_b[H + i];
        for (int m = 0; m < H; ++m) s += in_w[(H+i)*H + m] * bkv[m];
        wf[idx] = s;
    } else if (idx < WF_BV) {                // WvF[i][j]
        int r = idx - WF_WV; int i = r / AC, j = r % AC;
        float s = 0.f;
        for (int m = 0; m < H; ++m) s += in_w[(2*H+i)*H + m] * Wkv[(H+m)*AC + j];
        wf[idx] = s;
    } else if (idx < WF_WO) {                // bvF
        int i = idx - WF_BV;
        float s = in_b[2*H + i];
        for (int m = 0; m < H; ++m) s += in_w[(2*H+i)*H + m] * bkv[H + m];
        wf[idx] = s;
    } else if (idx < WF_BO) {                // WoF[c][d]
        int r = idx - WF_WO; int c = r >> 6, d = r & 63;
        float s = 0.f;
        for (int m = 0; m < H; ++m) s += proj_w[c*H + m] * out_w[m*H + d];
        wf[idx] = s;
    } else {                                 // boF
        int c = idx - WF_BO;
        float s = proj_b[c];
        for (int m = 0; m < H; ++m) s += proj_w[c*H + m] * out_b[m];
        wf[idx] = s;
    }
}

// ---------------- K1: fused QKV projection (wave-specialized, 12 sections/row) ----------------
__global__ __launch_bounds__(192) void k_qkv(
    const float* __restrict__ sem, const float* __restrict__ acst,
    const float* __restrict__ wf,
    u16* __restrict__ Qb, u16* __restrict__ Kb, u16* __restrict__ Vtb) {
    const int tid = threadIdx.x;
    const int sec = tid >> 4, r = tid & 15;
    const int row = blockIdx.x * 16 + r;
    const int b = row >> 10, t = row & 1023;
    const int type = sec >> 2, h = sec & 3;
    float o[16];
    if (type == 0) {
        float s[SE];
        const float4* sp = (const float4*)(sem + (size_t)row * SE);
        #pragma unroll
        for (int i = 0; i < 4; ++i) {
            float4 v = sp[i];
            s[4*i] = v.x; s[4*i+1] = v.y; s[4*i+2] = v.z; s[4*i+3] = v.w;
        }
        const float* wq = wf + WF_WQ + h*16*SE;
        const float* bq = wf + WF_BQ + h*16;
        #pragma unroll
        for (int ii = 0; ii < 16; ++ii) {
            float acc = bq[ii];
            #pragma unroll
            for (int j = 0; j < 4; ++j) {
                float4 w4 = *(const float4*)(wq + ii*SE + 4*j);
                acc += s[4*j]*w4.x + s[4*j+1]*w4.y + s[4*j+2]*w4.z + s[4*j+3]*w4.w;
            }
            o[ii] = acc;
        }
        unsigned* dst = (unsigned*)(Qb + (((size_t)(b*NH + h))*T + t)*16);
        #pragma unroll
        for (int i = 0; i < 8; ++i) dst[i] = packbf(o[2*i], o[2*i+1]);
    } else {
        float a[AC];
        const float4* ap = (const float4*)(acst + (size_t)row * AC);
        #pragma unroll
        for (int i = 0; i < 5; ++i) {
            float4 v = ap[i];
            a[4*i] = v.x; a[4*i+1] = v.y; a[4*i+2] = v.z; a[4*i+3] = v.w;
        }
        const float* wb = wf + (type == 1 ? WF_WK : WF_WV) + h*16*AC;
        const float* bb = wf + (type == 1 ? WF_BK : WF_BV) + h*16;
        #pragma unroll
        for (int ii = 0; ii < 16; ++ii) {
            float acc = bb[ii];
            #pragma unroll
            for (int j = 0; j < 5; ++j) {
                float4 w4 = *(const float4*)(wb + ii*AC + 4*j);
                acc += a[4*j]*w4.x + a[4*j+1]*w4.y + a[4*j+2]*w4.z + a[4*j+3]*w4.w;
            }
            o[ii] = acc;
        }
        if (type == 1) {
            unsigned* dst = (unsigned*)(Kb + (((size_t)(b*NH + h))*T + t)*16);
            #pragma unroll
            for (int i = 0; i < 8; ++i) dst[i] = packbf(o[2*i], o[2*i+1]);
        } else {
            int w32 = t & 31;
            int slot = (w32 < 16) ? (w32*2) : ((w32-16)*2 + 1);
            int tp = (t & ~31) | slot;
            #pragma unroll
            for (int d = 0; d < HD; ++d)
                Vtb[((size_t)(b*NH + h)*16 + d)*T + tp] = bf16b(o[d]);
        }
    }
}

// ---------------- K2: MFMA flash attention ----------------
// block = 8 waves (512 thr); wave = 32 q-rows x 512-key slice
// grid = 1024: idx bits = [0:3)=bh-low, [3:6)=qs (ks,qb), [6:10)=bh-high
__global__ __launch_bounds__(512) void k_attn(
    const u16* __restrict__ Qb, const u16* __restrict__ Kb, const u16* __restrict__ Vtb,
    float* __restrict__ part, float* __restrict__ partL) {
    __shared__ __align__(16) uint4 Ks2[NCH*64];     // 16 KB, [ch][frag][lane] (lane-linear reads)
    __shared__ __align__(16) uint4 Vs2[NCH*64];     // 16 KB, [chunk][lane]
    __shared__ __align__(16) u16 Ps[8*2*640];       // 20 KB (per wave: 2 tiles x 16x40)
    const int tid = threadIdx.x;
    const int idx = blockIdx.x;
    const int bh = (idx & 7) + 8 * (idx >> 6);
    const int qs = (idx >> 3) & 7;
    const int ks = qs & 1;
    const int qb = qs >> 1;            // 0..3
    const int kbase = ks * KSLICE;
    const int wv = tid >> 6, lane = tid & 63;
    const int col = lane & 15, quad = lane >> 4;
    const int q0 = qb*256 + wv*32;
    // Q fragments for both 16-row tiles (global; overlaps staging)
    short8 qf0 = {0,0,0,0,0,0,0,0}, qf1 = {0,0,0,0,0,0,0,0};
    if (quad < 2) {
        qf0 = *(const short8*)(Qb + ((size_t)bh*T + q0 + col)*16 + quad*8);
        qf1 = *(const short8*)(Qb + ((size_t)bh*T + q0 + 16 + col)*16 + quad*8);
    }
    // stage K [ch][frag][quad<2][col] and V [ch][lane]
    {
        const uint4* ksrc = (const uint4*)(Kb + ((size_t)bh*T + kbase)*16);
        #pragma unroll
        for (int s = tid; s < NCH*64; s += 512) {
            int src = (s & ~63) | (((s >> 5) & 1) * 32) | ((s & 15) * 2) | ((s >> 4) & 1);
            Ks2[s] = ksrc[src];
        }
        #pragma unroll
        for (int s = tid; s < NCH*64; s += 512) {
            int ch = s >> 6, ln = s & 63, d = ln & 15, qd = ln >> 4;
            Vs2[s] = *(const uint4*)(Vtb + ((size_t)(bh*16 + d))*T + kbase + ch*32 + qd*8);
        }
    }
    __syncthreads();
    const floatx4 z4 = {0.f,0.f,0.f,0.f};
    floatx4 acc0 = z4, acc1 = z4;
    float ls0[4] = {0.f,0.f,0.f,0.f}, ls1[4] = {0.f,0.f,0.f,0.f};
    u16* Pw0 = &Ps[wv*1280];
    u16* Pw1 = &Ps[wv*1280 + 640];
    short8 kc0 = {0,0,0,0,0,0,0,0}, kc1 = {0,0,0,0,0,0,0,0};
    if (quad < 2) {
        kc0 = *(const short8*)&Ks2[lane];
        kc1 = *(const short8*)&Ks2[32 + lane];
    }
    for (int ch = 0; ch < NCH; ++ch) {
        // QK^T for both q-tiles against this chunk's 32 keys
        floatx4 s00 = __builtin_amdgcn_mfma_f32_16x16x32_bf16(qf0, kc0, z4, 0, 0, 0);
        floatx4 s01 = __builtin_amdgcn_mfma_f32_16x16x32_bf16(qf0, kc1, z4, 0, 0, 0);
        floatx4 s10 = __builtin_amdgcn_mfma_f32_16x16x32_bf16(qf1, kc0, z4, 0, 0, 0);
        floatx4 s11 = __builtin_amdgcn_mfma_f32_16x16x32_bf16(qf1, kc1, z4, 0, 0, 0);
        // prefetch next chunk's K fragments (independent of P round-trip)
        if (ch + 1 < NCH && quad < 2) {
            kc0 = *(const short8*)&Ks2[(ch+1)*64 + lane];
            kc1 = *(const short8*)&Ks2[(ch+1)*64 + 32 + lane];
        }
        float p00[4], p01[4], p10[4], p11[4];
        #pragma unroll
        for (int r = 0; r < 4; ++r) {
            p00[r] = exp2f(s00[r]); p01[r] = exp2f(s01[r]);
            p10[r] = exp2f(s10[r]); p11[r] = exp2f(s11[r]);
            ls0[r] += p00[r] + p01[r];
            ls1[r] += p10[r] + p11[r];
        }
        #pragma unroll
        for (int r = 0; r < 4; ++r) {
            *(unsigned*)&Pw0[(quad*4 + r)*40 + col*2] = packbf(p00[r], p01[r]);
            *(unsigned*)&Pw1[(quad*4 + r)*40 + col*2] = packbf(p10[r], p11[r]);
        }
        short8 pf0 = *(const short8*)&Pw0[col*40 + quad*8];
        short8 pf1 = *(const short8*)&Pw1[col*40 + quad*8];
        short8 vf = *(const short8*)&Vs2[ch*64 + lane];
        acc0 = __builtin_amdgcn_mfma_f32_16x16x32_bf16(pf0, vf, acc0, 0, 0, 0);
        acc1 = __builtin_amdgcn_mfma_f32_16x16x32_bf16(pf1, vf, acc1, 0, 0, 0);
    }
    float* dst = part + (((size_t)ks*BH + bh)*T + q0)*16;
    #pragma unroll
    for (int r = 0; r < 4; ++r) {
        dst[(quad*4 + r)*16 + col]        = acc0[r];
        dst[(16 + quad*4 + r)*16 + col]   = acc1[r];
    }
    #pragma unroll
    for (int m = 1; m < 16; m <<= 1) {
        #pragma unroll
        for (int r = 0; r < 4; ++r) {
            ls0[r] += __shfl_xor(ls0[r], m);
            ls1[r] += __shfl_xor(ls1[r], m);
        }
    }
    if (col == 0) {
        float* ld = partL + ((size_t)ks*BH + bh)*T + q0 + quad*4;
        #pragma unroll
        for (int r = 0; r < 4; ++r) { ld[r] = ls0[r]; ld[16 + r] = ls1[r]; }
    }
}

// ---------------- K3: combine partials + output proj + residual ----------------
// block = 320 threads, 32 rows; phase2: thread = (row, 2 channels); grid 1024
#define CSTR 65
__global__ __launch_bounds__(320) void k_proj(
    const float* __restrict__ part, const float* __restrict__ partL,
    const float* __restrict__ acst, const float* __restrict__ wf,
    const float* __restrict__ rlogit,
    float* __restrict__ enhT, float* __restrict__ aT) {
    __shared__ float ctxs[32*CSTR];                 // 8.3 KB
    __shared__ __align__(16) float wsm[AC*H + AC];  // 5.2 KB
    const int tid = threadIdx.x;
    if (tid >= 128) {  // phase-1-idle threads preload weights
        for (int i = tid - 128; i < AC*H + AC; i += 192) wsm[i] = wf[WF_WO + i];
    } else {
        const int r = tid & 31, h = tid >> 5;
        const int row = blockIdx.x*32 + r;
        const int b = row >> 10, t = row & 1023;
        const int bh = b*NH + h;
        float l = partL[(size_t)bh*T + t] + partL[(size_t)(BH + bh)*T + t];
        float inv = 1.f / l;
        const float4* pa = (const float4*)(part + ((size_t)bh*T + t)*16);
        const float4* pb = (const float4*)(part + ((size_t)(BH + bh)*T + t)*16);
        float* cd = &ctxs[r*CSTR + h*16];
        #pragma unroll
        for (int i = 0; i < 4; ++i) {
            float4 x = pa[i], y = pb[i];
            cd[4*i+0] = (x.x + y.x)*inv;
            cd[4*i+1] = (x.y + y.y)*inv;
            cd[4*i+2] = (x.z + y.z)*inv;
            cd[4*i+3] = (x.w + y.w)*inv;
        }
    }
    __syncthreads();
    const int r = tid & 31, cp = tid >> 5;   // cp in [0,10)
    const int row = blockIdx.x*32 + r;
    const int ch0 = cp*2, ch1 = cp*2 + 1;
    float s0 = wsm[AC*H + ch0], s1 = wsm[AC*H + ch1];
    const float4* w0 = (const float4*)(wsm + ch0*H);
    const float4* w1 = (const float4*)(wsm + ch1*H);
    const float* cr = &ctxs[r*CSTR];
    #pragma unroll
    for (int k = 0; k < 16; ++k) {
        float4 c4 = *(const float4*)(cr + 4*k);
        float4 a4 = w0[k], b4 = w1[k];
        s0 += c4.x*a4.x + c4.y*a4.y + c4.z*a4.z + c4.w*a4.w;
        s1 += c4.x*b4.x + c4.y*b4.y + c4.z*b4.z + c4.w*b4.w;
    }
    float sg = 1.f / (1.f + __expf(-rlogit[0]));
    float a0 = acst[(size_t)row*AC + ch0];
    float a1 = acst[(size_t)row*AC + ch1];
    float e0 = a0 + sg * s0, e1 = a1 + sg * s1;
    enhT[(size_t)ch0 * NROW + row] = e0;
    enhT[(size_t)ch1 * NROW + row] = e1;
    aT[(size_t)ch0 * NROW + row] = a0;
    aT[(size_t)ch1 * NROW + row] = a1;
}

// ---------------- K4: per-channel partial stats (64 slices/channel) ----------------
__global__ __launch_bounds__(256) void k_stats1(
    const float* __restrict__ aT, const float* __restrict__ enhT,
    float* __restrict__ pst) {
    int c = blockIdx.x >> 6, sl = blockIdx.x & 63;
    int base = sl * 512;
    const float* ac = aT  + (size_t)c*NROW + base;
    const float* ec = enhT + (size_t)c*NROW + base;
    int tid = threadIdx.x;
    float a0 = ac[tid], a1 = ac[tid + 256];
    float e0 = ec[tid], e1 = ec[tid + 256];
    float sa = a0 + a1, qa = a0*a0 + a1*a1;
    float se = e0 + e1, qe = e0*e0 + e1*e1;
    #pragma unroll
    for (int off = 32; off > 0; off >>= 1) {
        sa += __shfl_down(sa, off);
        qa += __shfl_down(qa, off);
        se += __shfl_down(se, off);
        qe += __shfl_down(qe, off);
    }
    __shared__ float rs[4][4];
    int w = tid >> 6;
    if ((tid & 63) == 0) { rs[w][0] = sa; rs[w][1] = qa; rs[w][2] = se; rs[w][3] = qe; }
    __syncthreads();
    if (tid == 0) {
        float A = 0.f, QA = 0.f, E = 0.f, QE = 0.f;
        for (int i = 0; i < 4; ++i) { A += rs[i][0]; QA += rs[i][1]; E += rs[i][2]; QE += rs[i][3]; }
        float* d = pst + (size_t)(c*64 + sl)*4;
        d[0] = A; d[1] = QA; d[2] = E; d[3] = QE;
    }
}

// ---------------- K5: combine stats + std-correction + LayerNorm ----------------
__global__ __launch_bounds__(128) void k_final(
    const float* __restrict__ enhT, const float* __restrict__ pst,
    const float* __restrict__ gamma, const float* __restrict__ beta,
    float* __restrict__ out) {
    __shared__ float acc_s[80];
    for (int i = threadIdx.x; i < 80; i += 128) {
        int c = i >> 2, j = i & 3;
        float s = 0.f;
        for (int sl = 0; sl < 64; ++sl) s += pst[(size_t)(c*64 + sl)*4 + j];
        acc_s[i] = s;
    }
    __syncthreads();
    int row = blockIdx.x * 128 + threadIdx.x;
    const float Nf = (float)NROW;
    float ef[AC];
    #pragma unroll
    for (int c = 0; c < AC; ++c) {
        float sa = acc_s[c*4+0], qa = acc_s[c*4+1];
        float se = acc_s[c*4+2], qe = acc_s[c*4+3];
        float mu  = sa / Nf;
        float va  = (qa - sa*sa/Nf) / (Nf - 1.f);
        float sda = sqrtf(fmaxf(va, 0.f));
        float osd = sda + 1e-8f;
        float ve  = (qe - se*se/Nf) / (Nf - 1.f);
        float sde = sqrtf(fmaxf(ve, 0.f));
        float ratio = (sde / osd) / (sda / osd + 1e-8f);
        float corr  = (ratio < 0.4f) ? (0.4f / ratio) : 1.f;
        float e = enhT[(size_t)c * NROW + row];
        ef[c] = (e - mu) * corr + mu;
    }
    float m = 0.f;
    #pragma unroll
    for (int c = 0; c < AC; ++c) m += ef[c];
    m *= (1.f / AC);
    float v = 0.f;
    #pragma unroll
    for (int c = 0; c < AC; ++c) { float d = ef[c] - m; v += d*d; }
    v *= (1.f / AC);
    float inv = rsqrtf(v + 1e-5f);
    float o[AC];
    #pragma unroll
    for (int c = 0; c < AC; ++c) o[c] = (ef[c] - m) * inv * gamma[c] + beta[c];
    float4* op = (float4*)(out + (size_t)row * AC);
    #pragma unroll
    for (int i = 0; i < 5; ++i)
        op[i] = make_float4(o[4*i], o[4*i+1], o[4*i+2], o[4*i+3]);
}

extern "C" void kernel_launch(void* const* d_in, const int* in_sizes, int n_in,
                              void* d_out, int out_size, void* d_ws, size_t ws_size,
                              hipStream_t stream) {
    (void)in_sizes; (void)n_in; (void)out_size; (void)ws_size;
    const float* acoustic = (const float*)d_in[0];
    const float* semantic = (const float*)d_in[1];
    const float* Wq     = (const float*)d_in[2];
    const float* bq     = (const float*)d_in[3];
    const float* Wkv    = (const float*)d_in[4];
    const float* bkv    = (const float*)d_in[5];
    const float* in_w   = (const float*)d_in[6];
    const float* in_b   = (const float*)d_in[7];
    const float* out_w  = (const float*)d_in[8];
    const float* out_b  = (const float*)d_in[9];
    const float* proj_w = (const float*)d_in[10];
    const float* proj_b = (const float*)d_in[11];
    const float* rlogit = (const float*)d_in[12];
    const float* gamma  = (const float*)d_in[13];
    const float* beta   = (const float*)d_in[14];
    float* ws = (float*)d_ws;
    u16* Qb  = (u16*)(ws + OFF_QB);
    u16* Kb  = (u16*)(ws + OFF_KB);
    u16* Vtb = (u16*)(ws + OFF_VT);
    float* part  = ws + OFF_PART;
    float* partL = ws + OFF_PARTL;
    float* enhT  = ws + OFF_ET;
    float* aT    = ws + OFF_AT;
    float* wf    = ws + OFF_WF;
    float* pst   = ws + OFF_PST;
    float* out = (float*)d_out;

    k_fuse<<<(WF_TOTAL + 255)/256, 256, 0, stream>>>(Wq, bq, Wkv, bkv, in_w, in_b,
                                                     out_w, out_b, proj_w, proj_b, wf);
    k_qkv<<<NROW/16, 192, 0, stream>>>(semantic, acoustic, wf, Qb, Kb, Vtb);
    k_attn<<<BH*4*KS, 512, 0, stream>>>(Qb, Kb, Vtb, part, partL);
    k_proj<<<NROW/32, 320, 0, stream>>>(part, partL, acoustic, wf, rlogit, enhT, aT);
    k_stats1<<<AC*64, 256, 0, stream>>>(aT, enhT, pst);
    k_final<<<NROW/128, 128, 0, stream>>>(enhT, pst, gamma, beta, out);
}